// Round 11
// baseline (668.340 us; speedup 1.0000x reference)
//
#include <hip/hip_runtime.h>
#include <math.h>
#include <stdint.h>

// DHVT block. Round 11: dwconv rewritten zero-LDS register-stencil (was 140us,
// 21% of total: LDS-staged, 3 blocks/CU, div/mod+9 ds_read per element).
// Now out-of-place A->B (in-place was only safe with the block-local tile).
// Workspace re-laid-out; all else identical to round-10 PASS (665us).
// B=128 N=197 C=384 H=6 HD=64 HID=1536 S=14 M=203. B*M=25984, B*P=25088.
#define B_   128
#define N_   197
#define C_   384
#define H_   6
#define HD_  64
#define HID_ 1536
#define S_   14
#define M_   203
#define P_   196
#define TC_  1152  // 3*C

typedef __bf16 bf16_t;
typedef __bf16 bf16x8 __attribute__((ext_vector_type(8)));
typedef float  f32x4  __attribute__((ext_vector_type(4)));

// ---- workspace layout (bytes), ws >= 239,075,328 proven in round 2.
// Region A [0, 77.07M):    QKVb (59.87M, steps qkv..attn) -> HBUF_A (77.07M, c1 out, dwconv in)
// Region B [77.07, 154.14M): XA (19.96M) -> AOUT (19.96M) -> XN2 (19.27M) -> HBUF_B (77.07M, dwconv out, c3 in)
// Region P [154.14, 194.05M): PROJ f32 (39.91M) -> Y f32 (38.54M, c3 out)
// X1 [194.05, 232.78M) f32. Weights+small tail after.
static constexpr size_t OFF_A    = 0;
static constexpr size_t OFF_B    = 77070336;
static constexpr size_t OFF_P    = 154140672;
static constexpr size_t OFF_X1   = 194052096;
static constexpr size_t OFF_WQ   = 232783872;   // qkv_wT bf16 [1152][384]
static constexpr size_t OFF_WP   = 233668608;   // proj_wT bf16 [384][384]
static constexpr size_t OFF_W1   = 233963520;   // c1_wT  bf16 [1536][384]
static constexpr size_t OFF_W3   = 235143168;   // c3_wT  bf16 [384][1536]
static constexpr size_t OFF_CLS2 = 236322816;   // f32 B*C
static constexpr size_t OFF_WSE  = 236519424;   // f32 B*C
static constexpr size_t WS_BYTES = 236716032;

__device__ __forceinline__ float gelu_f(float x) {
    return 0.5f * x * (1.0f + erff(x * 0.70710678118654752440f));
}
__device__ __forceinline__ float wave_sum(float v) {
    #pragma unroll
    for (int o = 32; o > 0; o >>= 1) v += __shfl_xor(v, o);
    return v;
}
__device__ __forceinline__ void gl_lds16(const void* g, void* l) {
    __builtin_amdgcn_global_load_lds(
        (const __attribute__((address_space(1))) uint32_t*)g,
        (__attribute__((address_space(3))) uint32_t*)l, 16, 0, 0);
}
__device__ __forceinline__ uint32_t pkbf(float a, float b) {
    uint16_t ua = __builtin_bit_cast(uint16_t, (bf16_t)a);
    uint16_t ub = __builtin_bit_cast(uint16_t, (bf16_t)b);
    return (uint32_t)ua | ((uint32_t)ub << 16);
}

// ---- weight transpose + f32->bf16: Wt[n][k] = bf16(W[k][n]). K,N multiples of 32.
__global__ __launch_bounds__(256) void k_wT(const float* __restrict__ W, bf16_t* __restrict__ Wt,
                                            int K, int N)
{
    __shared__ float t[32][33];
    int kb = blockIdx.x * 32, nb = blockIdx.y * 32;
    int tx = threadIdx.x & 31, ty = threadIdx.x >> 5;  // ty 0..7
    #pragma unroll
    for (int i = 0; i < 4; ++i)
        t[ty + i*8][tx] = W[(size_t)(kb + ty + i*8) * N + nb + tx];
    __syncthreads();
    #pragma unroll
    for (int i = 0; i < 4; ++i)
        Wt[(size_t)(nb + ty + i*8) * K + kb + tx] = (bf16_t)t[tx][ty + i*8];
}

// ---- LN over C=384, one wave per row -> bf16 rows [0,197) of xa (B,M,C)
__global__ __launch_bounds__(256) void k_ln1(const float* __restrict__ x,
        const float* __restrict__ g, const float* __restrict__ bt, bf16_t* __restrict__ xa)
{
    int row = blockIdx.x * 4 + (threadIdx.x >> 6);
    if (row >= B_ * N_) return;
    int lane = threadIdx.x & 63;
    int b = row / N_, n = row % N_;
    const float* xr = x + (size_t)row * C_;
    float v[6], s = 0.f, sq = 0.f;
    #pragma unroll
    for (int i = 0; i < 6; ++i) { v[i] = xr[lane + 64*i]; s += v[i]; sq += v[i]*v[i]; }
    s = wave_sum(s); sq = wave_sum(sq);
    float mean = s * (1.0f / C_);
    float var  = sq * (1.0f / C_) - mean * mean;
    float rstd = rsqrtf(var + 1e-5f);
    bf16_t* orow = xa + ((size_t)b * M_ + n) * C_;
    #pragma unroll
    for (int i = 0; i < 6; ++i) {
        int c = lane + 64*i;
        orow[c] = (bf16_t)((v[i] - mean) * rstd * g[c] + bt[c]);
    }
}

// ---- head tokens (fused head_mean; same summation order -> bitwise-identical hs).
__global__ __launch_bounds__(384) void k_head_tokens(const bf16_t* __restrict__ xa_in,
    const float* __restrict__ ht_w, const float* __restrict__ ht_b,
    const float* __restrict__ htn_g, const float* __restrict__ htn_b,
    const float* __restrict__ pos, bf16_t* __restrict__ xa)
{
    __shared__ float hs[C_];
    int b = blockIdx.x, c = threadIdx.x, lane = c & 63;
    float s = 0.f;
    for (int n = 0; n < N_; ++n) s += (float)xa_in[((size_t)b * M_ + n) * C_ + c];
    hs[c] = s * (1.0f / N_);
    __syncthreads();
    for (int h1 = 0; h1 < H_; ++h1) {
        float acc = ht_b[c];
        #pragma unroll 8
        for (int d = 0; d < HD_; ++d) acc += hs[h1*HD_ + d] * ht_w[d*C_ + c];
        float mean = wave_sum(acc) * (1.0f / HD_);
        float sq   = wave_sum(acc*acc) * (1.0f / HD_);
        float var  = sq - mean*mean;
        float nv = (acc - mean) * rsqrtf(var + 1e-5f) * htn_g[lane] + htn_b[lane];
        xa[((size_t)b*M_ + N_ + h1)*C_ + c] = (bf16_t)(gelu_f(nv) + pos[h1*C_ + c]);
    }
}

// ---- bf16 MFMA GEMM, 128x128 tile, BK=32, 256 threads (4 waves, 2x2), m97 structure.
// EPI 0: f32 out = acc+bias ; 1: bf16 out = gelu(BN(acc+bias)) ; 2: f32 out = BN(acc+bias) ;
// EPI 3: bf16 out = acc+bias
template<int EPI>
__global__ __launch_bounds__(256) void k_mgemm(
    const bf16_t* __restrict__ A, const bf16_t* __restrict__ Bt,
    float* __restrict__ Cf, bf16_t* __restrict__ Cb,
    const float* __restrict__ bias, const float* __restrict__ bng,
    const float* __restrict__ bnb, int K, int Nc)
{
    __shared__ __align__(16) bf16_t As[128*32];
    __shared__ __align__(16) bf16_t Bs[128*32];
    int tid = threadIdx.x;
    int wave = tid >> 6, lane = tid & 63;
    int wm = wave >> 1, wn = wave & 1;
    int m_base = blockIdx.y * 128, n_base = blockIdx.x * 128;

    int sr = tid >> 2, ss = tid & 3;
    int sk8 = ss ^ ((sr >> 1) & 3);
    const bf16_t* gA = A  + (size_t)(m_base + sr) * K + sk8 * 8;
    const bf16_t* gB = Bt + (size_t)(n_base + sr) * K + sk8 * 8;
    char* AsB = (char*)As; char* BsB = (char*)Bs;

    int lr = lane & 15, lk = lane >> 4;
    int slot = lk ^ ((lr >> 1) & 3);
    int a_off = wm*4096 + lr*64 + slot*16;
    int b_off = wn*4096 + lr*64 + slot*16;

    f32x4 acc[4][4];
    #pragma unroll
    for (int i = 0; i < 4; ++i)
        #pragma unroll
        for (int j = 0; j < 4; ++j) acc[i][j] = (f32x4){0.f,0.f,0.f,0.f};

    for (int k0 = 0; k0 < K; k0 += 32) {
        gl_lds16(gA + k0,                 AsB + tid*16);
        gl_lds16(gA + k0 + (size_t)64*K,  AsB + 4096 + tid*16);
        gl_lds16(gB + k0,                 BsB + tid*16);
        gl_lds16(gB + k0 + (size_t)64*K,  BsB + 4096 + tid*16);
        __syncthreads();
        bf16x8 af[4], bfr[4];
        #pragma unroll
        for (int i = 0; i < 4; ++i) {
            af[i]  = *(const bf16x8*)(AsB + a_off + i*1024);
            bfr[i] = *(const bf16x8*)(BsB + b_off + i*1024);
        }
        #pragma unroll
        for (int i = 0; i < 4; ++i)
            #pragma unroll
            for (int j = 0; j < 4; ++j)
                acc[i][j] = __builtin_amdgcn_mfma_f32_16x16x32_bf16(af[i], bfr[j], acc[i][j], 0, 0, 0);
        __syncthreads();
    }

    const float R_ = 0.99999500003749969f;  // rsqrt(1+1e-5)
    #pragma unroll
    for (int nf = 0; nf < 4; ++nf) {
        int n = n_base + wn*64 + nf*16 + lr;
        float bia = bias[n];
        float sc = 1.f, sh = 0.f;
        if (EPI == 1 || EPI == 2) { sc = bng[n] * R_; sh = bnb[n]; }
        #pragma unroll
        for (int mf = 0; mf < 4; ++mf) {
            size_t mrow = (size_t)m_base + wm*64 + mf*16 + lk*4;
            #pragma unroll
            for (int j = 0; j < 4; ++j) {
                float v = acc[mf][nf][j] + bia;
                if (EPI == 1 || EPI == 2) v = v * sc + sh;
                if (EPI == 1) v = gelu_f(v);
                if (EPI == 1 || EPI == 3) Cb[(mrow + j) * Nc + n] = (bf16_t)v;
                else                      Cf[(mrow + j) * Nc + n] = v;
            }
        }
    }
}

// ---- MFMA attention: one block per (b,h), 512 threads (8 waves). (validated round 10)
__global__ __launch_bounds__(512) void k_attn_mfma(const bf16_t* __restrict__ qkv,
                                                   bf16_t* __restrict__ aout)
{
    __shared__ __align__(16) bf16_t Ks[224*64];   // content(r,s) = K[r][8*(s^(r&7)) ..+7]
    __shared__ __align__(16) bf16_t Vt[64][232];  // Vt[d][k] = V[k][d]; k>=203 zeroed
    int b = blockIdx.x / H_, h = blockIdx.x % H_;
    const bf16_t* qb = qkv + (size_t)b * M_ * TC_ + h * HD_;
    const bf16_t* kb = qb + C_;
    const bf16_t* vb = qb + 2 * C_;
    int tid = threadIdx.x;

    #pragma unroll
    for (int it = 0; it < 4; ++it) {
        int idx = tid + it * 512;
        if (idx < 1792) {
            int r = idx >> 3, s = idx & 7;
            int sg = s ^ (r & 7);
            gl_lds16(kb + (size_t)r * TC_ + sg * 8, ((char*)Ks) + idx * 16);
        }
    }
    {
        int d0 = (tid & 31) * 2;
        uint16_t* vt0 = (uint16_t*)&Vt[d0][0];
        uint16_t* vt1 = (uint16_t*)&Vt[d0 + 1][0];
        for (int k = tid >> 5; k < 224; k += 16) {
            uint32_t u = 0;
            if (k < M_) u = *(const uint32_t*)(vb + (size_t)k * TC_ + d0);
            vt0[k] = (uint16_t)(u & 0xffff);
            vt1[k] = (uint16_t)(u >> 16);
        }
    }
    __syncthreads();

    int lane = tid & 63, wave = tid >> 6;
    int q16 = lane & 15, g = lane >> 4;
    int base4g = g * 4;
    int s0 = q16 + (g & 1) * 32, s1 = s0 + 16;
    bool sel = (lane >= 32);

    for (int qt = wave; qt < 13; qt += 8) {
        int qrow = qt * 16 + q16;
        bf16x8 qf0 = *(const bf16x8*)(qb + (size_t)qrow * TC_ + g * 8);
        bf16x8 qf1 = *(const bf16x8*)(qb + (size_t)qrow * TC_ + 32 + g * 8);

        f32x4 sacc[14];
        #pragma unroll
        for (int t = 0; t < 14; ++t) sacc[t] = (f32x4){0.f, 0.f, 0.f, 0.f};
        #pragma unroll
        for (int kt = 0; kt < 14; ++kt) {
            int r = kt * 16 + q16;
            const char* rowp = (const char*)Ks + r * 128;
            bf16x8 kf0 = *(const bf16x8*)(rowp + ((g ^ (r & 7)) * 16));
            bf16x8 kf1 = *(const bf16x8*)(rowp + (((4 + g) ^ (r & 7)) * 16));
            sacc[kt] = __builtin_amdgcn_mfma_f32_16x16x32_bf16(kf0, qf0, sacc[kt], 0, 0, 0);
            sacc[kt] = __builtin_amdgcn_mfma_f32_16x16x32_bf16(kf1, qf1, sacc[kt], 0, 0, 0);
        }

        float mx = -1e30f;
        #pragma unroll
        for (int t = 0; t < 14; ++t)
            #pragma unroll
            for (int j = 0; j < 4; ++j) {
                int key = 16 * t + base4g + j;
                float v = (key < M_) ? sacc[t][j] * 0.125f : -1e30f;
                sacc[t][j] = v;
                mx = fmaxf(mx, v);
            }
        mx = fmaxf(mx, __shfl_xor(mx, 16));
        mx = fmaxf(mx, __shfl_xor(mx, 32));
        float sm = 0.f;
        #pragma unroll
        for (int t = 0; t < 14; ++t)
            #pragma unroll
            for (int j = 0; j < 4; ++j) {
                float e = __expf(sacc[t][j] - mx);
                sacc[t][j] = e;
                sm += e;
            }
        sm += __shfl_xor(sm, 16);
        sm += __shfl_xor(sm, 32);
        float inv = 1.0f / sm;

        uint32_t plo[14], phi[14];
        #pragma unroll
        for (int t = 0; t < 14; ++t) {
            plo[t] = pkbf(sacc[t][0] * inv, sacc[t][1] * inv);
            phi[t] = pkbf(sacc[t][2] * inv, sacc[t][3] * inv);
        }

        f32x4 oacc[4];
        #pragma unroll
        for (int dt = 0; dt < 4; ++dt) oacc[dt] = (f32x4){0.f, 0.f, 0.f, 0.f};
        #pragma unroll
        for (int c = 0; c < 7; ++c) {
            uint32_t l0a = (uint32_t)__shfl((int)plo[2*c],     s0);
            uint32_t l1a = (uint32_t)__shfl((int)plo[2*c + 1], s0);
            uint32_t h0a = (uint32_t)__shfl((int)phi[2*c],     s0);
            uint32_t h1a = (uint32_t)__shfl((int)phi[2*c + 1], s0);
            uint32_t l0b = (uint32_t)__shfl((int)plo[2*c],     s1);
            uint32_t l1b = (uint32_t)__shfl((int)plo[2*c + 1], s1);
            uint32_t h0b = (uint32_t)__shfl((int)phi[2*c],     s1);
            uint32_t h1b = (uint32_t)__shfl((int)phi[2*c + 1], s1);
            union { uint32_t u[4]; bf16x8 v; } pf;
            pf.u[0] = sel ? l1a : l0a;
            pf.u[1] = sel ? h1a : h0a;
            pf.u[2] = sel ? l1b : l0b;
            pf.u[3] = sel ? h1b : h0b;
            #pragma unroll
            for (int dt = 0; dt < 4; ++dt) {
                bf16x8 vf = *(const bf16x8*)(&Vt[dt*16 + q16][c*32 + g*8]);
                oacc[dt] = __builtin_amdgcn_mfma_f32_16x16x32_bf16(pf.v, vf, oacc[dt], 0, 0, 0);
            }
        }

        #pragma unroll
        for (int dt = 0; dt < 4; ++dt)
            #pragma unroll
            for (int j = 0; j < 4; ++j) {
                int q = qt * 16 + base4g + j;
                if (q < M_)
                    aout[((size_t)b * M_ + q) * C_ + h * HD_ + dt * 16 + q16] = (bf16_t)oacc[dt][j];
            }
    }
}

// ---- FUSED build_x1 + LN2 (validated round 10).
__global__ __launch_bounds__(256) void k_x1ln2(const float* __restrict__ x,
    const float* __restrict__ proj, const float* __restrict__ g, const float* __restrict__ bt,
    float* __restrict__ x1, bf16_t* __restrict__ xn2, float* __restrict__ cls2)
{
    int row = blockIdx.x * 4 + (threadIdx.x >> 6);
    if (row >= B_ * N_) return;
    int lane = threadIdx.x & 63;
    int b = row / N_, n = row % N_;
    const float* xr = x + (size_t)row * C_;
    const float* pr = proj + (size_t)b * M_ * C_;
    float v[6], s = 0.f, sq = 0.f;
    #pragma unroll
    for (int i = 0; i < 6; ++i) {
        int c = lane + 64*i;
        float t;
        if (n == 0) {
            float m = 0.f;
            #pragma unroll
            for (int mm = 0; mm < H_; ++mm) m += pr[(size_t)(N_ + mm) * C_ + c];
            t = xr[c] + pr[c] + m * (1.0f / H_);
        } else {
            t = xr[c] + pr[(size_t)n * C_ + c];
        }
        v[i] = t; s += t; sq += t*t;
    }
    float* x1r = x1 + (size_t)row * C_;
    #pragma unroll
    for (int i = 0; i < 6; ++i) x1r[lane + 64*i] = v[i];
    s = wave_sum(s); sq = wave_sum(sq);
    float mean = s * (1.0f / C_);
    float var  = sq * (1.0f / C_) - mean * mean;
    float rstd = rsqrtf(var + 1e-5f);
    #pragma unroll
    for (int i = 0; i < 6; ++i) {
        int c = lane + 64*i;
        float ov = (v[i] - mean) * rstd * g[c] + bt[c];
        if (n == 0) cls2[(size_t)b * C_ + c] = ov;
        else        xn2[((size_t)b * P_ + (n - 1)) * C_ + c] = (bf16_t)ov;
    }
}

// ---- depthwise 3x3 SAME + BN + gelu + residual, REWRITTEN: zero LDS, one thread
// per (b,y,ch), 3x14 input rows in registers, fully unrolled sliding stencil.
// Out-of-place hin->hout (in-place raced across y-neighbor blocks).
// FMA order identical to old kernel (dy outer, dx inner, OOB skipped) -> bitwise-same.
__global__ __launch_bounds__(256) void k_dwconv2(const bf16_t* __restrict__ hin,
    bf16_t* __restrict__ hout, const float* __restrict__ w, const float* __restrict__ c2b,
    const float* __restrict__ g2, const float* __restrict__ b2)
{
    int by = blockIdx.x;                 // b*14 + y
    int b = by / S_, y = by % S_;
    int ch = blockIdx.y * 256 + threadIdx.x;   // consecutive tid -> consecutive ch (coalesced)
    const bf16_t* base = hin + (size_t)b * P_ * HID_ + ch;

    float v[3][14];
    #pragma unroll
    for (int dy = 0; dy < 3; ++dy) {
        int yy = y + dy - 1;
        bool ok = (yy >= 0) && (yy < S_);
        #pragma unroll
        for (int xx = 0; xx < S_; ++xx)
            v[dy][xx] = ok ? (float)base[(size_t)(yy * S_ + xx) * HID_] : 0.f;
    }
    float wl[9];
    #pragma unroll
    for (int k = 0; k < 9; ++k) wl[k] = w[ch * 9 + k];
    const float R_ = 0.99999500003749969f;
    float bc = c2b[ch], gg = g2[ch] * R_, bb = b2[ch];

    bf16_t* obase = hout + ((size_t)b * P_ + y * S_) * HID_ + ch;
    #pragma unroll
    for (int x = 0; x < S_; ++x) {
        float a = 0.f;
        #pragma unroll
        for (int dy = 0; dy < 3; ++dy)
            #pragma unroll
            for (int dx = 0; dx < 3; ++dx) {
                int xx = x + dx - 1;
                if (xx < 0 || xx >= S_) continue;
                a += wl[dy*3 + dx] * v[dy][xx];
            }
        float val = (a + bc) * gg + bb;
        obase[(size_t)x * HID_] = (bf16_t)(v[1][x] + gelu_f(val));
    }
}

// ---- SE (fused ymean; validated round 10).
__global__ __launch_bounds__(384) void k_se(const float* __restrict__ y,
    const float* __restrict__ cw, const float* __restrict__ cb,
    const float* __restrict__ ew, const float* __restrict__ eb, float* __restrict__ wse)
{
    __shared__ float ys[C_];
    __shared__ float hid[96];
    int b = blockIdx.x, t = threadIdx.x;
    float s = 0.f;
    for (int p = 0; p < P_; ++p) s += y[((size_t)b * P_ + p) * C_ + t];
    ys[t] = s * (1.0f / P_);
    __syncthreads();
    if (t < 96) {
        float a = cb[t];
        for (int c = 0; c < C_; ++c) a += ys[c] * cw[c * 96 + t];
        hid[t] = gelu_f(a);
    }
    __syncthreads();
    float a = eb[t];
    #pragma unroll 8
    for (int j = 0; j < 96; ++j) a += hid[j] * ew[j * C_ + t];
    wse[b * C_ + t] = a;
}

// ---- out = x1 + [cls2*w, y tokens]
__global__ void k_final(const float* __restrict__ x1, const float* __restrict__ y,
    const float* __restrict__ cls2, const float* __restrict__ wse, float* __restrict__ out)
{
    size_t idx = (size_t)blockIdx.x * 256 + threadIdx.x;
    if (idx >= (size_t)B_*N_*C_) return;
    int c = (int)(idx % C_);
    size_t t = idx / C_;
    int n = (int)(t % N_); int b = (int)(t / N_);
    float v = x1[idx];
    if (n == 0) v += cls2[b*C_ + c] * wse[b*C_ + c];
    else        v += y[((size_t)b * P_ + (n - 1)) * C_ + c];
    out[idx] = v;
}

extern "C" void kernel_launch(void* const* d_in, const int* in_sizes, int n_in,
                              void* d_out, int out_size, void* d_ws, size_t ws_size,
                              hipStream_t stream)
{
    const float* x      = (const float*)d_in[0];
    const float* ln1_g  = (const float*)d_in[1];
    const float* ln1_b  = (const float*)d_in[2];
    const float* qkv_w  = (const float*)d_in[3];
    const float* qkv_b  = (const float*)d_in[4];
    const float* proj_w = (const float*)d_in[5];
    const float* proj_b = (const float*)d_in[6];
    const float* ht_w   = (const float*)d_in[7];
    const float* ht_b   = (const float*)d_in[8];
    const float* htn_g  = (const float*)d_in[9];
    const float* htn_b  = (const float*)d_in[10];
    const float* pos    = (const float*)d_in[11];
    const float* ln2_g  = (const float*)d_in[12];
    const float* ln2_b  = (const float*)d_in[13];
    const float* c1_w   = (const float*)d_in[14];
    const float* c1_b   = (const float*)d_in[15];
    const float* bn1_g  = (const float*)d_in[16];
    const float* bn1_b  = (const float*)d_in[17];
    const float* c2_w   = (const float*)d_in[18];
    const float* c2_b   = (const float*)d_in[19];
    const float* bn2_g  = (const float*)d_in[20];
    const float* bn2_b  = (const float*)d_in[21];
    const float* c3_w   = (const float*)d_in[22];
    const float* c3_b   = (const float*)d_in[23];
    const float* bn3_g  = (const float*)d_in[24];
    const float* bn3_b  = (const float*)d_in[25];
    const float* cmp_w  = (const float*)d_in[26];
    const float* cmp_b  = (const float*)d_in[27];
    const float* exc_w  = (const float*)d_in[28];
    const float* exc_b  = (const float*)d_in[29];

    if (ws_size < WS_BYTES) return;
    char* ws = (char*)d_ws;
    bf16_t* QKVb  = (bf16_t*)(ws + OFF_A);    // (B,M,3C) bf16, dead after attn
    bf16_t* HBUFA = (bf16_t*)(ws + OFF_A);    // (B,196,HID) bf16: c1 out, dwconv in
    bf16_t* XA    = (bf16_t*)(ws + OFF_B);    // (B,M,C) bf16
    bf16_t* AOUT  = (bf16_t*)(ws + OFF_B);    // (B,M,C) bf16 (after qkv gemm)
    bf16_t* XN2   = (bf16_t*)(ws + OFF_B);    // (B,196,C) bf16 (after proj)
    bf16_t* HBUFB = (bf16_t*)(ws + OFF_B);    // (B,196,HID) bf16: dwconv out, c3 in
    float*  PROJ  = (float*)(ws + OFF_P);     // (B,M,C) f32
    float*  Y     = (float*)(ws + OFF_P);     // (B,196,C) f32 (c3 out; PROJ dead)
    float*  X1    = (float*)(ws + OFF_X1);
    bf16_t* WQT   = (bf16_t*)(ws + OFF_WQ);
    bf16_t* WPT   = (bf16_t*)(ws + OFF_WP);
    bf16_t* W1T   = (bf16_t*)(ws + OFF_W1);
    bf16_t* W3T   = (bf16_t*)(ws + OFF_W3);
    float*  CLS2  = (float*)(ws + OFF_CLS2);
    float*  WSE   = (float*)(ws + OFF_WSE);

    k_wT<<<dim3(C_/32,  TC_/32), 256, 0, stream>>>(qkv_w,  WQT, C_,  TC_);
    k_wT<<<dim3(C_/32,  C_/32),  256, 0, stream>>>(proj_w, WPT, C_,  C_);
    k_wT<<<dim3(C_/32,  HID_/32),256, 0, stream>>>(c1_w,   W1T, C_,  HID_);
    k_wT<<<dim3(HID_/32,C_/32),  256, 0, stream>>>(c3_w,   W3T, HID_, C_);

    k_ln1<<<(B_*N_ + 3) / 4, 256, 0, stream>>>(x, ln1_g, ln1_b, XA);
    k_head_tokens<<<B_, 384, 0, stream>>>(XA, ht_w, ht_b, htn_g, htn_b, pos, XA);

    k_mgemm<3><<<dim3(TC_/128, (B_*M_)/128), 256, 0, stream>>>(
        XA, WQT, nullptr, QKVb, qkv_b, nullptr, nullptr, C_, TC_);

    k_attn_mfma<<<B_*H_, 512, 0, stream>>>(QKVb, AOUT);

    k_mgemm<0><<<dim3(C_/128, (B_*M_)/128), 256, 0, stream>>>(
        AOUT, WPT, PROJ, nullptr, proj_b, nullptr, nullptr, C_, C_);

    k_x1ln2<<<(B_*N_ + 3) / 4, 256, 0, stream>>>(x, PROJ, ln2_g, ln2_b, X1, XN2, CLS2);

    k_mgemm<1><<<dim3(HID_/128, (B_*P_)/128), 256, 0, stream>>>(
        XN2, W1T, nullptr, HBUFA, c1_b, bn1_g, bn1_b, C_, HID_);

    k_dwconv2<<<dim3(B_*S_, HID_/256), 256, 0, stream>>>(HBUFA, HBUFB, c2_w, c2_b, bn2_g, bn2_b);

    k_mgemm<2><<<dim3(C_/128, (B_*P_)/128), 256, 0, stream>>>(
        HBUFB, W3T, Y, nullptr, c3_b, bn3_g, bn3_b, HID_, C_);

    k_se<<<B_, 384, 0, stream>>>(Y, cmp_w, cmp_b, exc_w, exc_b, WSE);
    k_final<<<(B_*N_*C_ + 255)/256, 256, 0, stream>>>(X1, Y, CLS2, WSE, (float*)d_out);
}